// Round 2
// baseline (10314.875 us; speedup 1.0000x reference)
//
#include <hip/hip_runtime.h>
#include <hip/hip_bf16.h>

#define T_ 12
#define N_ 10000
#define C_ 32
#define E_ 320000
#define SUP_ 3
#define TN_ (T_*N_)

// prm layout (float offsets)
#define PRM_ATTN 0
#define PRM_G    64
#define PRM_H    1088
#define PRM_G1   2112
#define PRM_G2   2144
#define PRM_HB   2176
#define PRM_G0   2208

// ---------------- small precompute: attn vector + folded attention mats ----------------
__global__ __launch_bounds__(256) void k_prep(
    const float* __restrict__ timeoh, const float* __restrict__ temb_w,
    const float* __restrict__ atten_pool,
    const float* __restrict__ q_w, const float* __restrict__ q_b,
    const float* __restrict__ k_w, const float* __restrict__ k_b,
    const float* __restrict__ v_w, const float* __restrict__ v_b,
    const float* __restrict__ dense_w, const float* __restrict__ dense_b,
    float* __restrict__ prm) {
  __shared__ float tv[8];
  int tid = threadIdx.x;
  if (tid < 8) {
    float s = 0.f;
    for (int j = 0; j < 43; j++) s += timeoh[j] * temb_w[j * 8 + tid];
    tv[tid] = s;
  }
  __syncthreads();
  if (tid < 64) {
    float s = 0.f;
    for (int d = 0; d < 8; d++) s += tv[d] * atten_pool[d * 64 + tid];
    prm[PRM_ATTN + tid] = s;
  }
  for (int idx = tid; idx < 1024; idx += 256) {
    int r = idx >> 5, c = idx & 31;
    float s = 0.f, s2 = 0.f;
    for (int d = 0; d < 192; d++) {
      s  += q_w[r * 192 + d] * k_w[c * 192 + d];    // G = q_w @ k_w^T
      s2 += v_w[r * 192 + d] * dense_w[d * 32 + c]; // H = v_w @ dense_w
    }
    prm[PRM_G + idx] = s;
    prm[PRM_H + idx] = s2;
  }
  if (tid < 32) {
    float s = 0.f, s2 = 0.f, s3 = 0.f;
    for (int d = 0; d < 192; d++) {
      s  += q_w[tid * 192 + d] * k_b[d];
      s2 += k_w[tid * 192 + d] * q_b[d];
      s3 += v_b[d] * dense_w[d * 32 + tid];
    }
    prm[PRM_G1 + tid] = s;
    prm[PRM_G2 + tid] = s2;
    prm[PRM_HB + tid] = s3 + dense_b[tid];
  }
  if (tid == 0) {
    float s = 0.f;
    for (int d = 0; d < 192; d++) s += q_b[d] * k_b[d];
    prm[PRM_G0] = s;
  }
}

// ---------------- h = x@mlp_w+mlp_b (bf16 out), s_src/s_dst = h . attn halves ----------
__global__ __launch_bounds__(256) void k_h(
    const float* __restrict__ x, const float* __restrict__ mlp_w,
    const float* __restrict__ mlp_b, const float* __restrict__ prm,
    __hip_bfloat16* __restrict__ h16, float* __restrict__ s_src,
    float* __restrict__ s_dst) {
  __shared__ float W[32 * 32];
  __shared__ float bsh[32], attnsh[64];
  __shared__ float xs[8][32];
  int tid = threadIdx.x;
  for (int i = tid; i < 1024; i += 256) W[i] = mlp_w[i];
  if (tid < 32) bsh[tid] = mlp_b[tid];
  if (tid < 64) attnsh[tid] = prm[PRM_ATTN + tid];
  long base = (long)blockIdx.x * 8;
  int nloc = tid >> 5, c = tid & 31;
  long row = base + nloc;  // flat t*N+n, grid sized exactly
  xs[nloc][c] = x[row * 32 + c];
  __syncthreads();
  float hval = bsh[c];
#pragma unroll
  for (int k = 0; k < 32; k++) hval = fmaf(xs[nloc][k], W[k * 32 + c], hval);
  h16[row * 32 + c] = __float2bfloat16(hval);
  float a = hval * attnsh[c], b = hval * attnsh[32 + c];
#pragma unroll
  for (int m = 16; m >= 1; m >>= 1) {
    a += __shfl_xor(a, m, 64);
    b += __shfl_xor(b, m, 64);
  }
  if (c == 0) { s_src[row] = a; s_dst[row] = b; }
}

// ---------------- CSR build ----------------
__global__ __launch_bounds__(256) void k_hist(const int* __restrict__ edges,
                                              int* __restrict__ cnt) {
  int sup = blockIdx.y;
  int e = blockIdx.x * 256 + threadIdx.x;
  const int* src = edges + (long)sup * 2 * E_;
  atomicAdd(&cnt[sup * N_ + src[e]], 1);
}

__global__ __launch_bounds__(1024) void k_scan(const int* __restrict__ cnt,
                                               int* __restrict__ offs,
                                               int* __restrict__ cur) {
  __shared__ int sh[1024];
  __shared__ int run;
  int sup = blockIdx.x, tid = threadIdx.x;
  if (tid == 0) run = 0;
  __syncthreads();
  for (int base = 0; base < N_; base += 1024) {
    int i = base + tid;
    int v = (i < N_) ? cnt[sup * N_ + i] : 0;
    sh[tid] = v;
    __syncthreads();
    for (int off = 1; off < 1024; off <<= 1) {
      int t = (tid >= off) ? sh[tid - off] : 0;
      __syncthreads();
      sh[tid] += t;
      __syncthreads();
    }
    int runv = run;
    int excl = runv + sh[tid] - v;
    if (i < N_) {
      offs[sup * (N_ + 1) + i] = excl;
      cur[sup * N_ + i] = excl;
    }
    __syncthreads();
    if (tid == 0) run = runv + sh[1023];
    __syncthreads();
  }
  if (tid == 0) offs[sup * (N_ + 1) + N_] = run;
}

__global__ __launch_bounds__(256) void k_fill(const int* __restrict__ edges,
                                              int* __restrict__ cur,
                                              int* __restrict__ csr) {
  int sup = blockIdx.y;
  int e = blockIdx.x * 256 + threadIdx.x;
  const int* src = edges + (long)sup * 2 * E_;
  const int* dst = src + E_;
  int pos = atomicAdd(&cur[sup * N_ + src[e]], 1);
  csr[sup * E_ + pos] = dst[e];
}

// ---------------- global max of leaky(values) per (sup,t), order-encoded atomicMax -----
__global__ __launch_bounds__(256) void k_max(const int* __restrict__ edges,
                                             const float* __restrict__ s_src,
                                             const float* __restrict__ s_dst,
                                             unsigned* __restrict__ menc) {
  int sup = blockIdx.z, t = blockIdx.y;
  const int* src = edges + (long)sup * 2 * E_;
  const int* dst = src + E_;
  const float* ss = s_src + (long)t * N_;
  const float* sd = s_dst + (long)t * N_;
  float m = -1e30f;
  int lim = (blockIdx.x + 1) * 10000;
  for (int e = blockIdx.x * 10000 + threadIdx.x; e < lim; e += 256) {
    float v = ss[src[e]] + sd[dst[e]];
    v = (v >= 0.f) ? v : 0.01f * v;
    m = fmaxf(m, v);
  }
#pragma unroll
  for (int k = 32; k >= 1; k >>= 1) m = fmaxf(m, __shfl_xor(m, k, 64));
  if ((threadIdx.x & 63) == 0) {
    unsigned bits = __float_as_uint(m);
    unsigned enc = (bits & 0x80000000u) ? ~bits : (bits | 0x80000000u);
    atomicMax(&menc[sup * T_ + t], enc);
  }
}

// ---------------- GAT gather: one wave per (sup,t,n); elu fused ----------------
__global__ __launch_bounds__(256) void k_gather(
    const int* __restrict__ csr, const int* __restrict__ offs,
    const float* __restrict__ s_src, const float* __restrict__ s_dst,
    const unsigned* __restrict__ menc, const __hip_bfloat16* __restrict__ h16,
    __hip_bfloat16* __restrict__ hp16) {
  const int sup = blockIdx.z, t = blockIdx.y;
  const int wave = threadIdx.x >> 6, lane = threadIdx.x & 63;
  const int n = blockIdx.x * 4 + wave;
  unsigned enc = menc[sup * T_ + t];
  unsigned mb = (enc & 0x80000000u) ? (enc & 0x7fffffffu) : ~enc;
  const float M = __uint_as_float(mb);
  const float a = s_src[(long)t * N_ + n];
  const int off = offs[sup * (N_ + 1) + n], end = offs[sup * (N_ + 1) + n + 1];
  const float* sd = s_dst + (long)t * N_;
  const __hip_bfloat16* hb = h16 + (long)t * N_ * 32;
  const int c = lane & 31;
  const int half = lane & 32;
  float acc0 = 0.f, acc1 = 0.f, psum = 0.f;
  for (int base = off; base < end; base += 64) {
    int idx = base + lane;
    int d = 0;
    float p = 0.f;
    if (idx < end) {
      d = csr[sup * E_ + idx];
      float v = a + sd[d];
      v = (v >= 0.f) ? v : 0.01f * v;
      p = __expf(v - M);
      psum += p;
    }
#pragma unroll 8
    for (int j = 0; j < 32; j += 2) {
      int j0 = j + half, j1 = j + 1 + half;
      float p0 = __shfl(p, j0, 64);
      int d0 = __shfl(d, j0, 64);
      float p1 = __shfl(p, j1, 64);
      int d1 = __shfl(d, j1, 64);
      if (p0 != 0.f) acc0 = fmaf(p0, __bfloat162float(hb[(long)d0 * 32 + c]), acc0);
      if (p1 != 0.f) acc1 = fmaf(p1, __bfloat162float(hb[(long)d1 * 32 + c]), acc1);
    }
  }
  float acc = acc0 + acc1;
  acc += __shfl_xor(acc, 32, 64);
#pragma unroll
  for (int k = 32; k >= 1; k >>= 1) psum += __shfl_xor(psum, k, 64);
  if (lane < 32) {
    float hv = acc / (psum + 9e-15f);
    hv = (hv > 0.f) ? hv : (__expf(hv) - 1.f);
    hp16[((long)sup * TN_ + (long)t * N_ + n) * 32 + c] = __float2bfloat16(hv);
  }
}

// ---------------- fused adj@X, adj never materialized; PASS1 also accumulates R --------
// grid (157 w-tiles, 8 K-splits); out += P @ in  (atomic f32), X staged bf16 in LDS
template <int PASS>
__global__ __launch_bounds__(256) void k_adj(const float* __restrict__ n2v,
                                             const float* __restrict__ in,
                                             const float* __restrict__ Rin,
                                             float* __restrict__ out,
                                             float* __restrict__ Rout) {
  __shared__ float n2vwT[32][65];
  __shared__ float n2vvT[32][33];
  __shared__ float P[32][64];
  __shared__ __align__(16) unsigned short Bsh[32][384];
  const int tid = threadIdx.x;
  const int w0 = blockIdx.x * 64;
  const int v0 = blockIdx.y * 1250;
  const int v1 = v0 + 1250;
  for (int i = tid; i < 64 * 32; i += 256) {
    int w = i >> 5, k = i & 31;
    n2vwT[k][w] = (w0 + w < N_) ? n2v[(long)(w0 + w) * 32 + k] : 0.f;
  }
  float acc[8][12];
#pragma unroll
  for (int i = 0; i < 8; i++)
#pragma unroll
    for (int j = 0; j < 12; j++) acc[i][j] = 0.f;
  float Rreg = 0.f;
  const int wg = tid >> 5, tg = tid & 31;
  const int lw = tid & 63, vgrp = tid >> 6;
  for (int vb = v0; vb < v1; vb += 32) {
    __syncthreads();  // protect prev-iteration P/Bsh readers
    for (int i = tid; i < 32 * 32; i += 256) {
      int v = i >> 5, k = i & 31;
      n2vvT[k][v] = (vb + v < v1) ? n2v[(long)(vb + v) * 32 + k] : 0.f;
    }
    for (int fi = tid; fi < 32 * 384; fi += 256) {
      int v = fi / 384, tf = fi - v * 384;
      int t = tf >> 5, f = tf & 31;
      float val = 0.f;
      if (vb + v < v1) {
        val = in[((long)t * N_ + (vb + v)) * 32 + f];
        if (PASS == 2) val *= Rin[vb + v];  // Rin holds 1/R (row-normalize prev pass)
      }
      __hip_bfloat16 bv = __float2bfloat16(val);
      Bsh[v][tf] = __builtin_bit_cast(unsigned short, bv);
    }
    __syncthreads();
    float pv[8];
#pragma unroll
    for (int ii = 0; ii < 8; ii++) {
      int vl = vgrp * 8 + ii;
      float s = 0.f;
#pragma unroll
      for (int k = 0; k < 32; k++) s = fmaf(n2vwT[k][lw], n2vvT[k][vl], s);
      pv[ii] = (vb + vl < v1) ? __expf(fmaxf(s, 0.f)) : 0.f;
    }
#pragma unroll
    for (int ii = 0; ii < 8; ii++) P[vgrp * 8 + ii][lw] = pv[ii];
    __syncthreads();
    if (PASS == 1 && tid < 64) {
      float r = 0.f;
#pragma unroll
      for (int v = 0; v < 32; v++) r += P[v][tid];
      Rreg += r;
    }
#pragma unroll 4
    for (int v = 0; v < 32; v++) {
      float pw[8];
#pragma unroll
      for (int i = 0; i < 8; i++) pw[i] = P[v][wg * 8 + i];
#pragma unroll
      for (int q = 0; q < 3; q++) {
        uint2 bb = *(const uint2*)&Bsh[v][(q * 32 + tg) * 4];
        float b0 = __uint_as_float(bb.x << 16);
        float b1 = __uint_as_float(bb.x & 0xffff0000u);
        float b2 = __uint_as_float(bb.y << 16);
        float b3 = __uint_as_float(bb.y & 0xffff0000u);
#pragma unroll
        for (int i = 0; i < 8; i++) {
          acc[i][q * 4 + 0] = fmaf(pw[i], b0, acc[i][q * 4 + 0]);
          acc[i][q * 4 + 1] = fmaf(pw[i], b1, acc[i][q * 4 + 1]);
          acc[i][q * 4 + 2] = fmaf(pw[i], b2, acc[i][q * 4 + 2]);
          acc[i][q * 4 + 3] = fmaf(pw[i], b3, acc[i][q * 4 + 3]);
        }
      }
    }
  }
  if (PASS == 1 && tid < 64 && (w0 + tid) < N_) atomicAdd(&Rout[w0 + tid], Rreg);
#pragma unroll
  for (int i = 0; i < 8; i++) {
    int w = w0 + wg * 8 + i;
    if (w < N_) {
#pragma unroll
      for (int q = 0; q < 3; q++) {
#pragma unroll
        for (int jj = 0; jj < 4; jj++) {
          int tf = (q * 32 + tg) * 4 + jj;
          int t = tf >> 5, f = tf & 31;
          atomicAdd(&out[((long)t * N_ + w) * 32 + f], acc[i][q * 4 + jj]);
        }
      }
    }
  }
}

__global__ __launch_bounds__(256) void k_rinv(float* __restrict__ R) {
  int i = blockIdx.x * 256 + threadIdx.x;
  if (i < N_) R[i] = 1.f / R[i];
}

// ---------------- x_adp = [x, x1/R, x2/R] @ gcn_w + gcn_b   (in-place over x2) --------
__global__ __launch_bounds__(256) void k_gcn(const float* __restrict__ x,
                                             const float* __restrict__ x1,
                                             float* __restrict__ x2io,
                                             const float* __restrict__ Rinv,
                                             const float* __restrict__ gcn_w,
                                             const float* __restrict__ gcn_b) {
  __shared__ float W[96 * 32];
  __shared__ float bsh[32];
  __shared__ float rows[8][96];
  int tid = threadIdx.x;
  for (int i = tid; i < 96 * 32; i += 256) W[i] = gcn_w[i];
  if (tid < 32) bsh[tid] = gcn_b[tid];
  long base = (long)blockIdx.x * 8;
  int nloc = tid >> 5, c = tid & 31;
  long row = base + nloc;
  long nIdx = row % N_;
  float ri = Rinv[nIdx];
  rows[nloc][c] = x[row * 32 + c];
  rows[nloc][32 + c] = x1[row * 32 + c] * ri;
  rows[nloc][64 + c] = x2io[row * 32 + c] * ri;
  __syncthreads();
  float o = bsh[c];
#pragma unroll
  for (int k = 0; k < 96; k++) o = fmaf(rows[nloc][k], W[k * 32 + c], o);
  __syncthreads();
  x2io[row * 32 + c] = o;
}

// ---------------- collapsed slot attention + mean + elu ----------------
__device__ __forceinline__ void load_row(int s, long r, const float* __restrict__ x,
                                         const __hip_bfloat16* __restrict__ hp16,
                                         const float* __restrict__ xadp, float* m) {
  if (s == 0 || s == 4) {
    const float4* p = (const float4*)((s == 0 ? x : xadp) + r * 32);
#pragma unroll
    for (int q = 0; q < 8; q++) {
      float4 v = p[q];
      m[q * 4 + 0] = v.x; m[q * 4 + 1] = v.y; m[q * 4 + 2] = v.z; m[q * 4 + 3] = v.w;
    }
  } else {
    const uint4* p = (const uint4*)(hp16 + ((long)(s - 1) * TN_ + r) * 32);
#pragma unroll
    for (int q = 0; q < 4; q++) {
      uint4 v = p[q];
      unsigned uu[4] = {v.x, v.y, v.z, v.w};
#pragma unroll
      for (int j = 0; j < 4; j++) {
        m[q * 8 + j * 2 + 0] = __uint_as_float(uu[j] << 16);
        m[q * 8 + j * 2 + 1] = __uint_as_float(uu[j] & 0xffff0000u);
      }
    }
  }
}

__global__ __launch_bounds__(256) void k_attn(const float* __restrict__ x,
                                              const __hip_bfloat16* __restrict__ hp16,
                                              const float* __restrict__ xadp,
                                              const float* __restrict__ prm,
                                              float* __restrict__ out) {
  __shared__ float Gs[1024], Hs[1024], g1s[32], g2s[32], hbs[32];
  __shared__ float g0sh;
  int tid = threadIdx.x;
  for (int i = tid; i < 1024; i += 256) { Gs[i] = prm[PRM_G + i]; Hs[i] = prm[PRM_H + i]; }
  if (tid < 32) { g1s[tid] = prm[PRM_G1 + tid]; g2s[tid] = prm[PRM_G2 + tid]; hbs[tid] = prm[PRM_HB + tid]; }
  if (tid == 0) g0sh = prm[PRM_G0];
  __syncthreads();
  long r = (long)blockIdx.x * 256 + tid;
  if (r >= TN_) return;
  float g0 = g0sh;
  float sc[5][5], d1[5], d2[5];
  float ms[32], mu[32], y[32];
#pragma unroll
  for (int s = 0; s < 5; s++) {
    load_row(s, r, x, hp16, xadp, ms);
    float a = 0.f, b = 0.f;
#pragma unroll
    for (int k = 0; k < 32; k++) { a = fmaf(ms[k], g1s[k], a); b = fmaf(ms[k], g2s[k], b); }
    d1[s] = a; d2[s] = b;
#pragma unroll
    for (int c = 0; c < 32; c++) {
      float s2 = 0.f;
#pragma unroll
      for (int k = 0; k < 32; k++) s2 = fmaf(ms[k], Gs[k * 32 + c], s2);
      y[c] = s2;
    }
#pragma unroll
    for (int u = 0; u < 5; u++) {
      load_row(u, r, x, hp16, xadp, mu);
      float dt = 0.f;
#pragma unroll
      for (int k = 0; k < 32; k++) dt = fmaf(y[k], mu[k], dt);
      sc[s][u] = dt;
    }
  }
  const float rs = 0.07216878364870322f;  // 1/sqrt(192)
  float abar[5];
#pragma unroll
  for (int u = 0; u < 5; u++) abar[u] = 0.f;
#pragma unroll
  for (int s = 0; s < 5; s++) {
    float e[5];
    float mx = -1e30f;
#pragma unroll
    for (int u = 0; u < 5; u++) {
      float v = (sc[s][u] + d1[s] + d2[u] + g0) * rs;
      e[u] = v;
      mx = fmaxf(mx, v);
    }
    float sm = 0.f;
#pragma unroll
    for (int u = 0; u < 5; u++) { e[u] = __expf(e[u] - mx); sm += e[u]; }
    float inv = 1.f / sm;
#pragma unroll
    for (int u = 0; u < 5; u++) abar[u] = fmaf(e[u], inv, abar[u]);
  }
  float z[32];
#pragma unroll
  for (int k = 0; k < 32; k++) z[k] = 0.f;
#pragma unroll
  for (int u = 0; u < 5; u++) {
    load_row(u, r, x, hp16, xadp, mu);
    float w = abar[u] * 0.2f;
#pragma unroll
    for (int k = 0; k < 32; k++) z[k] = fmaf(w, mu[k], z[k]);
  }
#pragma unroll
  for (int c = 0; c < 32; c++) {
    float o = hbs[c];
#pragma unroll
    for (int k = 0; k < 32; k++) o = fmaf(z[k], Hs[k * 32 + c], o);
    o = (o > 0.f) ? o : (__expf(o) - 1.f);
    out[r * 32 + c] = o;
  }
}

// ---------------- launch ----------------
extern "C" void kernel_launch(void* const* d_in, const int* in_sizes, int n_in,
                              void* d_out, int out_size, void* d_ws, size_t ws_size,
                              hipStream_t stream) {
  (void)in_sizes; (void)n_in; (void)out_size; (void)ws_size;
  const float* x          = (const float*)d_in[0];
  const float* timeoh     = (const float*)d_in[1];
  const int*   edges      = (const int*)d_in[2];
  const float* mlp_w      = (const float*)d_in[3];
  const float* mlp_b      = (const float*)d_in[4];
  const float* temb_w     = (const float*)d_in[5];
  const float* atten_pool = (const float*)d_in[6];
  const float* node2vec   = (const float*)d_in[7];
  const float* gcn_w      = (const float*)d_in[8];
  const float* gcn_b      = (const float*)d_in[9];
  const float* q_w  = (const float*)d_in[10];
  const float* q_b  = (const float*)d_in[11];
  const float* k_w  = (const float*)d_in[12];
  const float* k_b  = (const float*)d_in[13];
  const float* v_w  = (const float*)d_in[14];
  const float* v_b  = (const float*)d_in[15];
  const float* dense_w = (const float*)d_in[16];
  const float* dense_b = (const float*)d_in[17];
  float* out = (float*)d_out;
  char* ws = (char*)d_ws;

  float*    prm  = (float*)(ws + 0);
  unsigned* menc = (unsigned*)(ws + 9216);
  int*      cnt  = (int*)(ws + 9472);
  int*      cur  = (int*)(ws + 129472);
  int*      offs = (int*)(ws + 249472);
  float*    ssrc = (float*)(ws + 369664);
  float*    sdst = (float*)(ws + 849664);
  float*    R    = (float*)(ws + 1329664);
  __hip_bfloat16* h16  = (__hip_bfloat16*)(ws + 1369664);
  int*      csr  = (int*)(ws + 9049664);
  __hip_bfloat16* hp16 = (__hip_bfloat16*)(ws + 12889664);
  float*    x1   = (float*)(ws + 35929664);
  float*    x2   = (float*)(ws + 51289664);

  (void)hipMemsetAsync(menc, 0, 144, stream);
  (void)hipMemsetAsync(cnt, 0, 120000, stream);
  (void)hipMemsetAsync(R, 0, 40000, stream);
  (void)hipMemsetAsync(x1, 0, 15360000, stream);
  (void)hipMemsetAsync(x2, 0, 15360000, stream);

  k_prep<<<1, 256, 0, stream>>>(timeoh, temb_w, atten_pool, q_w, q_b, k_w, k_b,
                                v_w, v_b, dense_w, dense_b, prm);
  k_h<<<15000, 256, 0, stream>>>(x, mlp_w, mlp_b, prm, h16, ssrc, sdst);
  k_hist<<<dim3(1250, 3), 256, 0, stream>>>(edges, cnt);
  k_scan<<<3, 1024, 0, stream>>>(cnt, offs, cur);
  k_fill<<<dim3(1250, 3), 256, 0, stream>>>(edges, cur, csr);
  k_max<<<dim3(32, 12, 3), 256, 0, stream>>>(edges, ssrc, sdst, menc);
  k_gather<<<dim3(2500, 12, 3), 256, 0, stream>>>(csr, offs, ssrc, sdst, menc, h16, hp16);
  k_adj<1><<<dim3(157, 8), 256, 0, stream>>>(node2vec, x, R, x1, R);
  k_rinv<<<40, 256, 0, stream>>>(R);
  k_adj<2><<<dim3(157, 8), 256, 0, stream>>>(node2vec, x1, R, x2, R);
  k_gcn<<<15000, 256, 0, stream>>>(x, x1, x2, R, gcn_w, gcn_b);
  k_attn<<<469, 256, 0, stream>>>(x, hp16, x2, prm, out);
}

// Round 3
// 2514.420 us; speedup vs baseline: 4.1023x; 4.1023x over previous
//
#include <hip/hip_runtime.h>
#include <hip/hip_bf16.h>

#define T_ 12
#define N_ 10000
#define C_ 32
#define E_ 320000
#define SUP_ 3
#define TN_ (T_*N_)

typedef __attribute__((ext_vector_type(4))) float f32x4;
typedef __attribute__((ext_vector_type(8))) short bf16x8;
typedef __attribute__((ext_vector_type(4))) short bf16x4;

__device__ __forceinline__ short bf16c(float f) {
  __hip_bfloat16 b = __float2bfloat16(f);
  return (short)__builtin_bit_cast(unsigned short, b);
}

// prm layout (float offsets)
#define PRM_ATTN 0
#define PRM_G    64
#define PRM_H    1088
#define PRM_G1   2112
#define PRM_G2   2144
#define PRM_HB   2176
#define PRM_G0   2208

// ---------------- small precompute: attn vector + folded attention mats ----------------
__global__ __launch_bounds__(256) void k_prep(
    const float* __restrict__ timeoh, const float* __restrict__ temb_w,
    const float* __restrict__ atten_pool,
    const float* __restrict__ q_w, const float* __restrict__ q_b,
    const float* __restrict__ k_w, const float* __restrict__ k_b,
    const float* __restrict__ v_w, const float* __restrict__ v_b,
    const float* __restrict__ dense_w, const float* __restrict__ dense_b,
    float* __restrict__ prm) {
  __shared__ float tv[8];
  int tid = threadIdx.x;
  if (tid < 8) {
    float s = 0.f;
    for (int j = 0; j < 43; j++) s += timeoh[j] * temb_w[j * 8 + tid];
    tv[tid] = s;
  }
  __syncthreads();
  if (tid < 64) {
    float s = 0.f;
    for (int d = 0; d < 8; d++) s += tv[d] * atten_pool[d * 64 + tid];
    prm[PRM_ATTN + tid] = s;
  }
  for (int idx = tid; idx < 1024; idx += 256) {
    int r = idx >> 5, c = idx & 31;
    float s = 0.f, s2 = 0.f;
    for (int d = 0; d < 192; d++) {
      s  += q_w[r * 192 + d] * k_w[c * 192 + d];    // G = q_w @ k_w^T
      s2 += v_w[r * 192 + d] * dense_w[d * 32 + c]; // H = v_w @ dense_w
    }
    prm[PRM_G + idx] = s;
    prm[PRM_H + idx] = s2;
  }
  if (tid < 32) {
    float s = 0.f, s2 = 0.f, s3 = 0.f;
    for (int d = 0; d < 192; d++) {
      s  += q_w[tid * 192 + d] * k_b[d];
      s2 += k_w[tid * 192 + d] * q_b[d];
      s3 += v_b[d] * dense_w[d * 32 + tid];
    }
    prm[PRM_G1 + tid] = s;
    prm[PRM_G2 + tid] = s2;
    prm[PRM_HB + tid] = s3 + dense_b[tid];
  }
  if (tid == 0) {
    float s = 0.f;
    for (int d = 0; d < 192; d++) s += q_b[d] * k_b[d];
    prm[PRM_G0] = s;
  }
}

// ---------------- h = x@mlp_w+mlp_b (bf16 out), s_src/s_dst = h . attn halves ----------
__global__ __launch_bounds__(256) void k_h(
    const float* __restrict__ x, const float* __restrict__ mlp_w,
    const float* __restrict__ mlp_b, const float* __restrict__ prm,
    __hip_bfloat16* __restrict__ h16, float* __restrict__ s_src,
    float* __restrict__ s_dst) {
  __shared__ float W[32 * 32];
  __shared__ float bsh[32], attnsh[64];
  __shared__ float xs[8][32];
  int tid = threadIdx.x;
  for (int i = tid; i < 1024; i += 256) W[i] = mlp_w[i];
  if (tid < 32) bsh[tid] = mlp_b[tid];
  if (tid < 64) attnsh[tid] = prm[PRM_ATTN + tid];
  long base = (long)blockIdx.x * 8;
  int nloc = tid >> 5, c = tid & 31;
  long row = base + nloc;  // flat t*N+n, grid sized exactly
  xs[nloc][c] = x[row * 32 + c];
  __syncthreads();
  float hval = bsh[c];
#pragma unroll
  for (int k = 0; k < 32; k++) hval = fmaf(xs[nloc][k], W[k * 32 + c], hval);
  h16[row * 32 + c] = __float2bfloat16(hval);
  float a = hval * attnsh[c], b = hval * attnsh[32 + c];
#pragma unroll
  for (int m = 16; m >= 1; m >>= 1) {
    a += __shfl_xor(a, m, 64);
    b += __shfl_xor(b, m, 64);
  }
  if (c == 0) { s_src[row] = a; s_dst[row] = b; }
}

// ---------------- CSR build ----------------
__global__ __launch_bounds__(256) void k_hist(const int* __restrict__ edges,
                                              int* __restrict__ cnt) {
  int sup = blockIdx.y;
  int e = blockIdx.x * 256 + threadIdx.x;
  const int* src = edges + (long)sup * 2 * E_;
  atomicAdd(&cnt[sup * N_ + src[e]], 1);
}

__global__ __launch_bounds__(1024) void k_scan(const int* __restrict__ cnt,
                                               int* __restrict__ offs,
                                               int* __restrict__ cur) {
  __shared__ int sh[1024];
  __shared__ int run;
  int sup = blockIdx.x, tid = threadIdx.x;
  if (tid == 0) run = 0;
  __syncthreads();
  for (int base = 0; base < N_; base += 1024) {
    int i = base + tid;
    int v = (i < N_) ? cnt[sup * N_ + i] : 0;
    sh[tid] = v;
    __syncthreads();
    for (int off = 1; off < 1024; off <<= 1) {
      int t = (tid >= off) ? sh[tid - off] : 0;
      __syncthreads();
      sh[tid] += t;
      __syncthreads();
    }
    int runv = run;
    int excl = runv + sh[tid] - v;
    if (i < N_) {
      offs[sup * (N_ + 1) + i] = excl;
      cur[sup * N_ + i] = excl;
    }
    __syncthreads();
    if (tid == 0) run = runv + sh[1023];
    __syncthreads();
  }
  if (tid == 0) offs[sup * (N_ + 1) + N_] = run;
}

__global__ __launch_bounds__(256) void k_fill(const int* __restrict__ edges,
                                              int* __restrict__ cur,
                                              int* __restrict__ csr) {
  int sup = blockIdx.y;
  int e = blockIdx.x * 256 + threadIdx.x;
  const int* src = edges + (long)sup * 2 * E_;
  const int* dst = src + E_;
  int pos = atomicAdd(&cur[sup * N_ + src[e]], 1);
  csr[sup * E_ + pos] = dst[e];
}

// ---------------- global max of leaky(values) per (sup,t), order-encoded atomicMax -----
__global__ __launch_bounds__(256) void k_max(const int* __restrict__ edges,
                                             const float* __restrict__ s_src,
                                             const float* __restrict__ s_dst,
                                             unsigned* __restrict__ menc) {
  int sup = blockIdx.z, t = blockIdx.y;
  const int* src = edges + (long)sup * 2 * E_;
  const int* dst = src + E_;
  const float* ss = s_src + (long)t * N_;
  const float* sd = s_dst + (long)t * N_;
  float m = -1e30f;
  int lim = (blockIdx.x + 1) * 10000;
  for (int e = blockIdx.x * 10000 + threadIdx.x; e < lim; e += 256) {
    float v = ss[src[e]] + sd[dst[e]];
    v = (v >= 0.f) ? v : 0.01f * v;
    m = fmaxf(m, v);
  }
#pragma unroll
  for (int k = 32; k >= 1; k >>= 1) m = fmaxf(m, __shfl_xor(m, k, 64));
  if ((threadIdx.x & 63) == 0) {
    unsigned bits = __float_as_uint(m);
    unsigned enc = (bits & 0x80000000u) ? ~bits : (bits | 0x80000000u);
    atomicMax(&menc[sup * T_ + t], enc);
  }
}

// ---------------- GAT gather: one wave per (sup,t,n); elu fused ----------------
__global__ __launch_bounds__(256) void k_gather(
    const int* __restrict__ csr, const int* __restrict__ offs,
    const float* __restrict__ s_src, const float* __restrict__ s_dst,
    const unsigned* __restrict__ menc, const __hip_bfloat16* __restrict__ h16,
    __hip_bfloat16* __restrict__ hp16) {
  const int sup = blockIdx.z, t = blockIdx.y;
  const int wave = threadIdx.x >> 6, lane = threadIdx.x & 63;
  const int n = blockIdx.x * 4 + wave;
  unsigned enc = menc[sup * T_ + t];
  unsigned mb = (enc & 0x80000000u) ? (enc & 0x7fffffffu) : ~enc;
  const float M = __uint_as_float(mb);
  const float a = s_src[(long)t * N_ + n];
  const int off = offs[sup * (N_ + 1) + n], end = offs[sup * (N_ + 1) + n + 1];
  const float* sd = s_dst + (long)t * N_;
  const __hip_bfloat16* hb = h16 + (long)t * N_ * 32;
  const int c = lane & 31;
  const int half = lane & 32;
  float acc0 = 0.f, acc1 = 0.f, psum = 0.f;
  for (int base = off; base < end; base += 64) {
    int idx = base + lane;
    int d = 0;
    float p = 0.f;
    if (idx < end) {
      d = csr[sup * E_ + idx];
      float v = a + sd[d];
      v = (v >= 0.f) ? v : 0.01f * v;
      p = __expf(v - M);
      psum += p;
    }
#pragma unroll 8
    for (int j = 0; j < 32; j += 2) {
      int j0 = j + half, j1 = j + 1 + half;
      float p0 = __shfl(p, j0, 64);
      int d0 = __shfl(d, j0, 64);
      float p1 = __shfl(p, j1, 64);
      int d1 = __shfl(d, j1, 64);
      if (p0 != 0.f) acc0 = fmaf(p0, __bfloat162float(hb[(long)d0 * 32 + c]), acc0);
      if (p1 != 0.f) acc1 = fmaf(p1, __bfloat162float(hb[(long)d1 * 32 + c]), acc1);
    }
  }
  float acc = acc0 + acc1;
  acc += __shfl_xor(acc, 32, 64);
#pragma unroll
  for (int k = 32; k >= 1; k >>= 1) psum += __shfl_xor(psum, k, 64);
  if (lane < 32) {
    float hv = acc / (psum + 9e-15f);
    hv = (hv > 0.f) ? hv : (__expf(hv) - 1.f);
    hp16[((long)sup * TN_ + (long)t * N_ + n) * 32 + c] = __float2bfloat16(hv);
  }
}

// ---------------- MFMA fused adj@X (adj never materialized) ----------------------------
// out(10000x384) += P @ in, P[w][v] = exp(relu(n2v[w].n2v[v])), PASS1 also accumulates R.
// BM=128 (4 Mtiles x 2 wave-Mgroups), BN=384 (6 Ntiles x 4 wave-Ngroups), BK=32, Ksplit=5.
// S^T trick: mfma(n2vV, n2vW^T) C/D regs land directly in the A-frag layout for P@X.
template <int PASS>
__global__ __launch_bounds__(512) void k_adj2(const float* __restrict__ n2v,
                                              const float* __restrict__ in,
                                              const float* __restrict__ Rin,
                                              float* __restrict__ out,
                                              float* __restrict__ Rout) {
  __shared__ __align__(16) short xs[8 * 1536];  // [kq=vloc>>2][col(384)][vloc&3] bf16
  const int tid = threadIdx.x;
  const int lane = tid & 63;
  const int wv = tid >> 6;        // 0..7
  const int mgrp = wv >> 2;       // 0..1 : rows m0 + mgrp*64 ..
  const int ngrp = wv & 3;        // 0..3 : cols ngrp*96 ..
  const int l15 = lane & 15;
  const int l4 = lane >> 4;       // 0..3
  const int m0 = blockIdx.x * 128;
  const int cks = (313 * blockIdx.y) / 5;
  const int cke = (313 * (blockIdx.y + 1)) / 5;

  // B-frags of n2vW^T for this wave's 4 M-tiles (block-constant)
  bf16x8 bw[4];
#pragma unroll
  for (int mt = 0; mt < 4; mt++) {
    int row = m0 + mgrp * 64 + mt * 16 + l15;
    row = row < N_ ? row : N_ - 1;
    const float4 w0 = *(const float4*)&n2v[row * 32 + 4 * l4];
    const float4 w1 = *(const float4*)&n2v[row * 32 + 16 + 4 * l4];
    bw[mt] = bf16x8{bf16c(w0.x), bf16c(w0.y), bf16c(w0.z), bf16c(w0.w),
                    bf16c(w1.x), bf16c(w1.y), bf16c(w1.z), bf16c(w1.w)};
  }

  f32x4 acc[4][6];
#pragma unroll
  for (int i = 0; i < 4; i++)
#pragma unroll
    for (int j = 0; j < 6; j++) acc[i][j] = f32x4{0.f, 0.f, 0.f, 0.f};
  float racc[4] = {0.f, 0.f, 0.f, 0.f};

  const int skq = wv;   // staging: thread owns kq = wv, cols lane + 64q

  for (int ck = cks; ck < cke; ck++) {
    const int vb = ck * 32;
    const int valid = (N_ - vb < 32) ? (N_ - vb) : 32;

    float rv[4];
    if constexpr (PASS == 2) {
#pragma unroll
      for (int r = 0; r < 4; r++) {
        int v = vb + skq * 4 + r;
        rv[r] = (v < N_) ? Rin[v] : 0.f;
      }
    }

    __syncthreads();  // previous chunk's readers done with xs
    // ---- stage X chunk (32 v x 384 cols) as bf16, quad-k layout, b64 writes ----
#pragma unroll
    for (int q = 0; q < 6; q++) {
      const int col = lane + 64 * q;
      const int t = col >> 5, f = col & 31;
      short p0, p1, p2, p3;
      {
        const long cbase = ((long)t * N_ + vb) * 32 + f;
        const int v0 = skq * 4;
        float a0 = (v0 + 0 < valid) ? in[cbase + (long)(v0 + 0) * 32] : 0.f;
        float a1 = (v0 + 1 < valid) ? in[cbase + (long)(v0 + 1) * 32] : 0.f;
        float a2 = (v0 + 2 < valid) ? in[cbase + (long)(v0 + 2) * 32] : 0.f;
        float a3 = (v0 + 3 < valid) ? in[cbase + (long)(v0 + 3) * 32] : 0.f;
        if constexpr (PASS == 2) { a0 *= rv[0]; a1 *= rv[1]; a2 *= rv[2]; a3 *= rv[3]; }
        p0 = bf16c(a0); p1 = bf16c(a1); p2 = bf16c(a2); p3 = bf16c(a3);
      }
      *(bf16x4*)&xs[skq * 1536 + col * 4] = bf16x4{p0, p1, p2, p3};
    }

    // ---- n2vV A-frags for S^T (two v-halves), direct float4 from global ----
    bf16x8 av[2];
#pragma unroll
    for (int vh = 0; vh < 2; vh++) {
      int row = vb + vh * 16 + l15;
      row = row < N_ ? row : N_ - 1;
      const float4 a0 = *(const float4*)&n2v[row * 32 + 4 * l4];
      const float4 a1 = *(const float4*)&n2v[row * 32 + 16 + 4 * l4];
      av[vh] = bf16x8{bf16c(a0.x), bf16c(a0.y), bf16c(a0.z), bf16c(a0.w),
                      bf16c(a1.x), bf16c(a1.y), bf16c(a1.z), bf16c(a1.w)};
    }

    // ---- P A-frags per M-tile: S^T = V.W^T, then relu+exp(+mask for R) ----
    bf16x8 aP[4];
#pragma unroll
    for (int mt = 0; mt < 4; mt++) {
      f32x4 s0 = __builtin_amdgcn_mfma_f32_16x16x32_bf16(av[0], bw[mt],
                                                         f32x4{0.f, 0.f, 0.f, 0.f}, 0, 0, 0);
      f32x4 s1 = __builtin_amdgcn_mfma_f32_16x16x32_bf16(av[1], bw[mt],
                                                         f32x4{0.f, 0.f, 0.f, 0.f}, 0, 0, 0);
      short pp[8];
      float rsum = 0.f;
#pragma unroll
      for (int j = 0; j < 4; j++) {
        float p0 = __expf(fmaxf(s0[j], 0.f));
        float p1 = __expf(fmaxf(s1[j], 0.f));
        if constexpr (PASS == 1) {
          int v0 = 4 * l4 + j, v1 = 16 + 4 * l4 + j;
          rsum += (v0 < valid ? p0 : 0.f) + (v1 < valid ? p1 : 0.f);
        }
        pp[j] = bf16c(p0);
        pp[j + 4] = bf16c(p1);
      }
      aP[mt] = bf16x8{pp[0], pp[1], pp[2], pp[3], pp[4], pp[5], pp[6], pp[7]};
      if constexpr (PASS == 1) racc[mt] += rsum;
    }

    __syncthreads();  // xs staged

    // ---- main MFMAs: acc[mt][it] += P_tile(mt) @ X_tile(it) ----
#pragma unroll
    for (int it = 0; it < 6; it++) {
      const int colb = (ngrp * 6 + it) * 16 + l15;
      bf16x4 x0 = *(const bf16x4*)&xs[(0 + l4) * 1536 + colb * 4];
      bf16x4 x1 = *(const bf16x4*)&xs[(4 + l4) * 1536 + colb * 4];
      bf16x8 bx = __builtin_shufflevector(x0, x1, 0, 1, 2, 3, 4, 5, 6, 7);
#pragma unroll
      for (int mt = 0; mt < 4; mt++)
        acc[mt][it] = __builtin_amdgcn_mfma_f32_16x16x32_bf16(aP[mt], bx, acc[mt][it], 0, 0, 0);
    }
  }

  // ---- epilogue ----
  if constexpr (PASS == 1) {
    if (ngrp == 0) {
#pragma unroll
      for (int mt = 0; mt < 4; mt++) {
        float r = racc[mt];
        r += __shfl_xor(r, 16, 64);
        r += __shfl_xor(r, 32, 64);
        int w = m0 + mgrp * 64 + mt * 16 + l15;
        if (l4 == 0 && w < N_) atomicAdd(&Rout[w], r);
      }
    }
  }
#pragma unroll
  for (int mt = 0; mt < 4; mt++) {
    const int wbase = m0 + mgrp * 64 + mt * 16;
#pragma unroll
    for (int it = 0; it < 6; it++) {
      const int col = (ngrp * 6 + it) * 16 + l15;
      const int t = col >> 5, f = col & 31;
#pragma unroll
      for (int j = 0; j < 4; j++) {
        const int w = wbase + 4 * l4 + j;
        if (w < N_) atomicAdd(&out[((long)t * N_ + w) * 32 + f], acc[mt][it][j]);
      }
    }
  }
}

__global__ __launch_bounds__(256) void k_rinv(float* __restrict__ R) {
  int i = blockIdx.x * 256 + threadIdx.x;
  if (i < N_) R[i] = 1.f / R[i];
}

// ---------------- x_adp = [x, x1/R, x2/R] @ gcn_w + gcn_b   (in-place over x2) --------
__global__ __launch_bounds__(256) void k_gcn(const float* __restrict__ x,
                                             const float* __restrict__ x1,
                                             float* __restrict__ x2io,
                                             const float* __restrict__ Rinv,
                                             const float* __restrict__ gcn_w,
                                             const float* __restrict__ gcn_b) {
  __shared__ float W[96 * 32];
  __shared__ float bsh[32];
  __shared__ float rows[8][96];
  int tid = threadIdx.x;
  for (int i = tid; i < 96 * 32; i += 256) W[i] = gcn_w[i];
  if (tid < 32) bsh[tid] = gcn_b[tid];
  long base = (long)blockIdx.x * 8;
  int nloc = tid >> 5, c = tid & 31;
  long row = base + nloc;
  long nIdx = row % N_;
  float ri = Rinv[nIdx];
  rows[nloc][c] = x[row * 32 + c];
  rows[nloc][32 + c] = x1[row * 32 + c] * ri;
  rows[nloc][64 + c] = x2io[row * 32 + c] * ri;
  __syncthreads();
  float o = bsh[c];
#pragma unroll
  for (int k = 0; k < 96; k++) o = fmaf(rows[nloc][k], W[k * 32 + c], o);
  __syncthreads();
  x2io[row * 32 + c] = o;
}

// ---------------- collapsed slot attention + mean + elu ----------------
__device__ __forceinline__ void load_row(int s, long r, const float* __restrict__ x,
                                         const __hip_bfloat16* __restrict__ hp16,
                                         const float* __restrict__ xadp, float* m) {
  if (s == 0 || s == 4) {
    const float4* p = (const float4*)((s == 0 ? x : xadp) + r * 32);
#pragma unroll
    for (int q = 0; q < 8; q++) {
      float4 v = p[q];
      m[q * 4 + 0] = v.x; m[q * 4 + 1] = v.y; m[q * 4 + 2] = v.z; m[q * 4 + 3] = v.w;
    }
  } else {
    const uint4* p = (const uint4*)(hp16 + ((long)(s - 1) * TN_ + r) * 32);
#pragma unroll
    for (int q = 0; q < 4; q++) {
      uint4 v = p[q];
      unsigned uu[4] = {v.x, v.y, v.z, v.w};
#pragma unroll
      for (int j = 0; j < 4; j++) {
        m[q * 8 + j * 2 + 0] = __uint_as_float(uu[j] << 16);
        m[q * 8 + j * 2 + 1] = __uint_as_float(uu[j] & 0xffff0000u);
      }
    }
  }
}

__global__ __launch_bounds__(256) void k_attn(const float* __restrict__ x,
                                              const __hip_bfloat16* __restrict__ hp16,
                                              const float* __restrict__ xadp,
                                              const float* __restrict__ prm,
                                              float* __restrict__ out) {
  __shared__ float Gs[1024], Hs[1024], g1s[32], g2s[32], hbs[32];
  __shared__ float g0sh;
  int tid = threadIdx.x;
  for (int i = tid; i < 1024; i += 256) { Gs[i] = prm[PRM_G + i]; Hs[i] = prm[PRM_H + i]; }
  if (tid < 32) { g1s[tid] = prm[PRM_G1 + tid]; g2s[tid] = prm[PRM_G2 + tid]; hbs[tid] = prm[PRM_HB + tid]; }
  if (tid == 0) g0sh = prm[PRM_G0];
  __syncthreads();
  long r = (long)blockIdx.x * 256 + tid;
  if (r >= TN_) return;
  float g0 = g0sh;
  float sc[5][5], d1[5], d2[5];
  float ms[32], mu[32], y[32];
#pragma unroll
  for (int s = 0; s < 5; s++) {
    load_row(s, r, x, hp16, xadp, ms);
    float a = 0.f, b = 0.f;
#pragma unroll
    for (int k = 0; k < 32; k++) { a = fmaf(ms[k], g1s[k], a); b = fmaf(ms[k], g2s[k], b); }
    d1[s] = a; d2[s] = b;
#pragma unroll
    for (int c = 0; c < 32; c++) {
      float s2 = 0.f;
#pragma unroll
      for (int k = 0; k < 32; k++) s2 = fmaf(ms[k], Gs[k * 32 + c], s2);
      y[c] = s2;
    }
#pragma unroll
    for (int u = 0; u < 5; u++) {
      load_row(u, r, x, hp16, xadp, mu);
      float dt = 0.f;
#pragma unroll
      for (int k = 0; k < 32; k++) dt = fmaf(y[k], mu[k], dt);
      sc[s][u] = dt;
    }
  }
  const float rs = 0.07216878364870322f;  // 1/sqrt(192)
  float abar[5];
#pragma unroll
  for (int u = 0; u < 5; u++) abar[u] = 0.f;
#pragma unroll
  for (int s = 0; s < 5; s++) {
    float e[5];
    float mx = -1e30f;
#pragma unroll
    for (int u = 0; u < 5; u++) {
      float v = (sc[s][u] + d1[s] + d2[u] + g0) * rs;
      e[u] = v;
      mx = fmaxf(mx, v);
    }
    float sm = 0.f;
#pragma unroll
    for (int u = 0; u < 5; u++) { e[u] = __expf(e[u] - mx); sm += e[u]; }
    float inv = 1.f / sm;
#pragma unroll
    for (int u = 0; u < 5; u++) abar[u] = fmaf(e[u], inv, abar[u]);
  }
  float z[32];
#pragma unroll
  for (int k = 0; k < 32; k++) z[k] = 0.f;
#pragma unroll
  for (int u = 0; u < 5; u++) {
    load_row(u, r, x, hp16, xadp, mu);
    float w = abar[u] * 0.2f;
#pragma unroll
    for (int k = 0; k < 32; k++) z[k] = fmaf(w, mu[k], z[k]);
  }
#pragma unroll
  for (int c = 0; c < 32; c++) {
    float o = hbs[c];
#pragma unroll
    for (int k = 0; k < 32; k++) o = fmaf(z[k], Hs[k * 32 + c], o);
    o = (o > 0.f) ? o : (__expf(o) - 1.f);
    out[r * 32 + c] = o;
  }
}

// ---------------- launch ----------------
extern "C" void kernel_launch(void* const* d_in, const int* in_sizes, int n_in,
                              void* d_out, int out_size, void* d_ws, size_t ws_size,
                              hipStream_t stream) {
  (void)in_sizes; (void)n_in; (void)out_size; (void)ws_size;
  const float* x          = (const float*)d_in[0];
  const float* timeoh     = (const float*)d_in[1];
  const int*   edges      = (const int*)d_in[2];
  const float* mlp_w      = (const float*)d_in[3];
  const float* mlp_b      = (const float*)d_in[4];
  const float* temb_w     = (const float*)d_in[5];
  const float* atten_pool = (const float*)d_in[6];
  const float* node2vec   = (const float*)d_in[7];
  const float* gcn_w      = (const float*)d_in[8];
  const float* gcn_b      = (const float*)d_in[9];
  const float* q_w  = (const float*)d_in[10];
  const float* q_b  = (const float*)d_in[11];
  const float* k_w  = (const float*)d_in[12];
  const float* k_b  = (const float*)d_in[13];
  const float* v_w  = (const float*)d_in[14];
  const float* v_b  = (const float*)d_in[15];
  const float* dense_w = (const float*)d_in[16];
  const float* dense_b = (const float*)d_in[17];
  float* out = (float*)d_out;
  char* ws = (char*)d_ws;

  float*    prm  = (float*)(ws + 0);
  unsigned* menc = (unsigned*)(ws + 9216);
  int*      cnt  = (int*)(ws + 9472);
  int*      cur  = (int*)(ws + 129472);
  int*      offs = (int*)(ws + 249472);
  float*    ssrc = (float*)(ws + 369664);
  float*    sdst = (float*)(ws + 849664);
  float*    R    = (float*)(ws + 1329664);
  __hip_bfloat16* h16  = (__hip_bfloat16*)(ws + 1369664);
  int*      csr  = (int*)(ws + 9049664);
  __hip_bfloat16* hp16 = (__hip_bfloat16*)(ws + 12889664);
  float*    x1   = (float*)(ws + 35929664);
  float*    x2   = (float*)(ws + 51289664);

  (void)hipMemsetAsync(menc, 0, 144, stream);
  (void)hipMemsetAsync(cnt, 0, 120000, stream);
  (void)hipMemsetAsync(R, 0, 40000, stream);
  (void)hipMemsetAsync(x1, 0, 15360000, stream);
  (void)hipMemsetAsync(x2, 0, 15360000, stream);

  k_prep<<<1, 256, 0, stream>>>(timeoh, temb_w, atten_pool, q_w, q_b, k_w, k_b,
                                v_w, v_b, dense_w, dense_b, prm);
  k_h<<<15000, 256, 0, stream>>>(x, mlp_w, mlp_b, prm, h16, ssrc, sdst);
  k_hist<<<dim3(1250, 3), 256, 0, stream>>>(edges, cnt);
  k_scan<<<3, 1024, 0, stream>>>(cnt, offs, cur);
  k_fill<<<dim3(1250, 3), 256, 0, stream>>>(edges, cur, csr);
  k_max<<<dim3(32, 12, 3), 256, 0, stream>>>(edges, ssrc, sdst, menc);
  k_gather<<<dim3(2500, 12, 3), 256, 0, stream>>>(csr, offs, ssrc, sdst, menc, h16, hp16);
  k_adj2<1><<<dim3(79, 5), 512, 0, stream>>>(node2vec, x, nullptr, x1, R);
  k_rinv<<<40, 256, 0, stream>>>(R);
  k_adj2<2><<<dim3(79, 5), 512, 0, stream>>>(node2vec, x1, R, x2, nullptr);
  k_gcn<<<15000, 256, 0, stream>>>(x, x1, x2, R, gcn_w, gcn_b);
  k_attn<<<469, 256, 0, stream>>>(x, hp16, x2, prm, out);
}